// Round 2
// baseline (79.363 us; speedup 1.0000x reference)
//
#include <hip/hip_runtime.h>
#include <hip/hip_fp16.h>

#define TPB 256
#define MAXGRID 2048

// Padded image: 68x68 texels, texel = half2(c0, c1). Padded index p maps to
// unpadded p-2, with 2-wide reflected border baked in at staging time.
#define PW 68

__device__ __forceinline__ void cubic_w(float t, float w[4]) {
    // A = -0.75 ; s = 1-t
    float s = 1.0f - t;
    float t2 = t * t;
    float s2 = s * s;
    w[0] = -0.75f * t * s2;                       // A*t*s^2
    w[1] = 1.25f * (t2 * t) - 2.25f * t2 + 1.0f;  // (A+2)t^3-(A+3)t^2+1
    w[2] = 1.25f * (s2 * s) - 2.25f * s2 + 1.0f;
    w[3] = -0.75f * s * t2;
}

__global__ __launch_bounds__(TPB, 8) void deformation_field_kernel(
        const float2* __restrict__ coord2,   // (y,x) per point
        const float4* __restrict__ depl4,    // 2*64*64 floats = 2048 float4
        const float4* __restrict__ mask4,
        float2* __restrict__ out2,           // (c0,c1) fp32 per point
        int n_pts)
{
    __shared__ __half2 img[PW * PW];  // 18,496 B -> 8 blocks/CU

    // ---- Phase 1: core 64x64 -> padded [2..65][2..65], masked, fp16-packed ----
    for (int i = threadIdx.x; i < 1024; i += TPB) {
        float4 d0 = depl4[i];          // channel 0, pixels 4i..4i+3
        float4 m0 = mask4[i];
        float4 d1 = depl4[1024 + i];   // channel 1
        float4 m1 = mask4[1024 + i];
        int o = i * 4;
        int r = o >> 6;
        int c = o & 63;                // 4-aligned, never crosses a row
        int pb = (r + 2) * PW + (c + 2);
        img[pb + 0] = __floats2half2_rn(d0.x * m0.x, d1.x * m1.x);
        img[pb + 1] = __floats2half2_rn(d0.y * m0.y, d1.y * m1.y);
        img[pb + 2] = __floats2half2_rn(d0.z * m0.z, d1.z * m1.z);
        img[pb + 3] = __floats2half2_rn(d0.w * m0.w, d1.w * m1.w);
    }
    __syncthreads();

    // ---- Phase 2a: reflected border columns for core rows ----
    // padded col 0 <- col 4, 1 <- 3, 66 <- 64, 67 <- 63
    {
        int t = threadIdx.x;           // exactly 256 threads: 64 rows x 4 cols
        int r = 2 + (t & 63);
        int j = t >> 6;                // 0..3
        int sel = j & 1, half = j >> 1;
        int dc = half ? (66 + sel) : sel;          // 0,1,66,67
        int sc = half ? (64 - sel) : (4 - sel);    // 4,3,64,63
        img[r * PW + dc] = img[r * PW + sc];
    }
    __syncthreads();

    // ---- Phase 2b: reflected border rows (full width, incl. corners) ----
    if (threadIdx.x < PW) {
        int c = threadIdx.x;
        img[0 * PW + c]  = img[4 * PW + c];
        img[1 * PW + c]  = img[3 * PW + c];
        img[66 * PW + c] = img[64 * PW + c];
        img[67 * PW + c] = img[63 * PW + c];
    }
    __syncthreads();

    // ---- Main: one point per thread, grid-stride with next-coord prefetch ----
    const int stride = gridDim.x * TPB;
    int p = blockIdx.x * TPB + threadIdx.x;
    if (p >= n_pts) return;            // after all barriers: safe

    float2 c = coord2[p];              // c.x = y-coord, c.y = x-coord
    for (;;) {
        int pn = p + stride;
        bool has = (pn < n_pts);
        float2 cn;
        if (has) cn = coord2[pn];      // issue early; hides under compute

        // crop = 1/64; ix = (x - crop + 1) * 31.5 = fma(x, 31.5, 31.0078125)
        float ix = fmaf(c.y, 31.5f, 31.0078125f);
        float iy = fmaf(c.x, 31.5f, 31.0078125f);
        float fx = floorf(ix);
        float fy = floorf(iy);
        float tx = ix - fx;
        float ty = iy - fy;
        int jx = (int)fx;              // [-1, 62]
        int jy = (int)fy;

        float wx[4], wy[4];
        cubic_w(tx, wx);
        cubic_w(ty, wy);
        __half2 wxh[4];
        #pragma unroll
        for (int k = 0; k < 4; ++k) wxh[k] = __float2half2_rn(wx[k]);

        // first tap col = jx-1 -> padded jx+1; rows likewise
        int base = (jy + 1) * PW + (jx + 1);

        float a0 = 0.0f, a1 = 0.0f;
        #pragma unroll
        for (int i = 0; i < 4; ++i) {
            int rb = base + i * PW;
            // packed fp16 x-pass: both channels per instruction, no cvts
            __half2 r = __hmul2(wxh[0], img[rb + 0]);
            r = __hfma2(wxh[1], img[rb + 1], r);
            r = __hfma2(wxh[2], img[rb + 2], r);
            r = __hfma2(wxh[3], img[rb + 3], r);
            // fp32 y-pass
            a0 = fmaf(wy[i], __low2float(r), a0);
            a1 = fmaf(wy[i], __high2float(r), a1);
        }
        out2[p] = make_float2(a0, a1);

        if (!has) break;
        p = pn;
        c = cn;
    }
}

extern "C" void kernel_launch(void* const* d_in, const int* in_sizes, int n_in,
                              void* d_out, int out_size, void* d_ws, size_t ws_size,
                              hipStream_t stream) {
    const float2* coord2 = (const float2*)d_in[0];  // (B,2) f32
    const float4* depl4  = (const float4*)d_in[1];  // (2,64,64) f32
    const float4* mask4  = (const float4*)d_in[2];  // (2,64,64) f32
    float2* out2 = (float2*)d_out;                  // (B,2) f32

    int n_pts = in_sizes[0] / 2;  // B points (in_sizes[0] = 2*B floats)
    // 2048 blocks -> 8 blocks/CU (18.5 KB LDS), 4 grid-stride iters/thread
    int grid = (n_pts + TPB - 1) / TPB;
    if (grid > MAXGRID) grid = MAXGRID;
    if (grid < 1) grid = 1;

    deformation_field_kernel<<<grid, TPB, 0, stream>>>(coord2, depl4, mask4, out2, n_pts);
}

// Round 3
// 76.015 us; speedup vs baseline: 1.0440x; 1.0440x over previous
//
#include <hip/hip_runtime.h>
#include <hip/hip_fp16.h>

#define TPB 1024
#define MAXGRID 512

// Padded image: 68x68 texels, texel = half2(c0, c1). Padded index p maps to
// unpadded p-2, reflected border baked in. Stored TWICE: copy A at dword 0,
// copy B (shifted by one texel: B[d] = A[d+1]) at dword OFFB, so any pair of
// consecutive taps is an aligned ds_read_b64 in the copy matching the
// starting column's parity.
#define PW 68
#define NPAD (PW * PW)   // 4624 dwords per copy
#define OFFB NPAD

__device__ __forceinline__ void cubic_w(float t, float w[4]) {
    // A = -0.75 ; s = 1-t
    float s = 1.0f - t;
    float t2 = t * t;
    float s2 = s * s;
    w[0] = -0.75f * t * s2;                       // A*t*s^2
    w[1] = 1.25f * (t2 * t) - 2.25f * t2 + 1.0f;  // (A+2)t^3-(A+3)t^2+1
    w[2] = 1.25f * (s2 * s) - 2.25f * s2 + 1.0f;
    w[3] = -0.75f * s * t2;
}

__global__ __launch_bounds__(TPB, 8) void deformation_field_kernel(
        const float2* __restrict__ coord2,   // (y,x) per point
        const float4* __restrict__ depl4,    // 2*64*64 floats = 2048 float4
        const float4* __restrict__ mask4,
        float2* __restrict__ out2,           // (c0,c1) fp32 per point
        int n_pts)
{
    __shared__ __half2 img[2 * NPAD];  // 36,992 B -> 2 blocks/CU, 32 waves/CU

    const int tid = threadIdx.x;

    // ---- Phase 1: core 64x64 -> copy A [2..65][2..65], masked, fp16 ----
    {
        int i = tid;                   // exactly 1024 groups of 4 texels
        float4 d0 = depl4[i];          // channel 0, pixels 4i..4i+3
        float4 m0 = mask4[i];
        float4 d1 = depl4[1024 + i];   // channel 1
        float4 m1 = mask4[1024 + i];
        int o = i * 4;
        int r = o >> 6;
        int c = o & 63;                // 4-aligned, never crosses a row
        int pb = (r + 2) * PW + (c + 2);
        img[pb + 0] = __floats2half2_rn(d0.x * m0.x, d1.x * m1.x);
        img[pb + 1] = __floats2half2_rn(d0.y * m0.y, d1.y * m1.y);
        img[pb + 2] = __floats2half2_rn(d0.z * m0.z, d1.z * m1.z);
        img[pb + 3] = __floats2half2_rn(d0.w * m0.w, d1.w * m1.w);
    }
    __syncthreads();

    // ---- Phase 2a: reflected border columns for core rows (copy A) ----
    // padded col 0 <- col 4, 1 <- 3, 66 <- 64, 67 <- 63
    if (tid < 256) {
        int r = 2 + (tid & 63);
        int j = tid >> 6;              // 0..3
        int sel = j & 1, half = j >> 1;
        int dc = half ? (66 + sel) : sel;          // 0,1,66,67
        int sc = half ? (64 - sel) : (4 - sel);    // 4,3,64,63
        img[r * PW + dc] = img[r * PW + sc];
    }
    __syncthreads();

    // ---- Phase 2b: reflected border rows, full width incl. corners ----
    // row 0 <- 4, 1 <- 3, 66 <- 64, 67 <- 63
    if (tid < 4 * PW) {
        int j = tid / PW;              // 0..3
        int c = tid - j * PW;
        int dr = (j & 2) ? (66 + (j & 1)) : (j & 1);        // 0,1,66,67
        int sr = (j & 2) ? (64 - (j & 1)) : (4 - (j & 1));  // 4,3,64,63
        img[dr * PW + c] = img[sr * PW + c];
    }
    __syncthreads();

    // ---- Phase 3: copy B = A shifted by one texel ----
    for (int d = tid; d < NPAD - 1; d += TPB)
        img[OFFB + d] = img[d + 1];
    __syncthreads();

    // ---- Main: one point per thread, grid-stride with next-coord prefetch ----
    const int stride = gridDim.x * TPB;
    int p = blockIdx.x * TPB + tid;
    if (p >= n_pts) return;            // after all barriers: safe

    float2 c = coord2[p];              // c.x = y-coord, c.y = x-coord
    for (;;) {
        int pn = p + stride;
        bool has = (pn < n_pts);
        float2 cn;
        if (has) cn = coord2[pn];      // issue early; hides under compute

        // crop = 1/64; ix = (x - crop + 1) * 31.5 = fma(x, 31.5, 31.0078125)
        float ix = fmaf(c.y, 31.5f, 31.0078125f);
        float iy = fmaf(c.x, 31.5f, 31.0078125f);
        float fx = floorf(ix);
        float fy = floorf(iy);
        float tx = ix - fx;
        float ty = iy - fy;
        int jxp = (int)fx + 1;         // padded first-tap col, [0, 63]
        int jyp = (int)fy + 1;         // padded first-tap row, [0, 63]

        float wx[4], wy[4];
        cubic_w(tx, wx);
        cubic_w(ty, wy);
        __half2 wxh[4];
        #pragma unroll
        for (int k = 0; k < 4; ++k) wxh[k] = __float2half2_rn(wx[k]);

        // parity-select: even start -> copy A at col jxp; odd -> copy B at col jxp-1
        int dbase = jyp * PW + (jxp & ~1) + ((jxp & 1) ? OFFB : 0);
        const __half2* bp = &img[dbase];

        float a0 = 0.0f, a1 = 0.0f;
        #pragma unroll
        for (int i = 0; i < 4; ++i) {
            // two aligned b64 reads: taps {0,1} and {2,3} of this row
            uint2 ua = *reinterpret_cast<const uint2*>(bp + i * PW);
            uint2 ub = *reinterpret_cast<const uint2*>(bp + i * PW + 2);
            __half2 t0 = *reinterpret_cast<const __half2*>(&ua.x);
            __half2 t1 = *reinterpret_cast<const __half2*>(&ua.y);
            __half2 t2 = *reinterpret_cast<const __half2*>(&ub.x);
            __half2 t3 = *reinterpret_cast<const __half2*>(&ub.y);
            // packed fp16 x-pass: both channels per instruction
            __half2 r = __hmul2(wxh[0], t0);
            r = __hfma2(wxh[1], t1, r);
            r = __hfma2(wxh[2], t2, r);
            r = __hfma2(wxh[3], t3, r);
            // fp32 y-pass
            a0 = fmaf(wy[i], __low2float(r), a0);
            a1 = fmaf(wy[i], __high2float(r), a1);
        }
        out2[p] = make_float2(a0, a1);

        if (!has) break;
        p = pn;
        c = cn;
    }
}

extern "C" void kernel_launch(void* const* d_in, const int* in_sizes, int n_in,
                              void* d_out, int out_size, void* d_ws, size_t ws_size,
                              hipStream_t stream) {
    const float2* coord2 = (const float2*)d_in[0];  // (B,2) f32
    const float4* depl4  = (const float4*)d_in[1];  // (2,64,64) f32
    const float4* mask4  = (const float4*)d_in[2];  // (2,64,64) f32
    float2* out2 = (float2*)d_out;                  // (B,2) f32

    int n_pts = in_sizes[0] / 2;  // B points (in_sizes[0] = 2*B floats)
    // 512 blocks of 1024 -> 2 blocks/CU (37 KB LDS), 32 waves/CU, 4 pts/thread
    int grid = (n_pts + TPB - 1) / TPB;
    if (grid > MAXGRID) grid = MAXGRID;
    if (grid < 1) grid = 1;

    deformation_field_kernel<<<grid, TPB, 0, stream>>>(coord2, depl4, mask4, out2, n_pts);
}